// Round 1
// baseline (499.070 us; speedup 1.0000x reference)
//
#include <hip/hip_runtime.h>

// GCN 2-layer fused pipeline for MI355X.
// Layer1 collapses to a scalar aggregation (input dim = 1).
// Layer2: dense h1@W2 (LDS-staged W2), CSR-gather aggregation fused with
// b2 + relu + @Wh + bh epilogue (wave-64 reduce, one wave per node).

__global__ void k_zero(int* __restrict__ p, int n) {
    int i = blockIdx.x * blockDim.x + threadIdx.x;
    if (i < n) p[i] = 0;
}

__global__ void k_deg(const int* __restrict__ dst, int* __restrict__ deg, int E) {
    int e = blockIdx.x * blockDim.x + threadIdx.x;
    if (e < E) atomicAdd(&deg[dst[e]], 1);
}

// Per-block exclusive scan (1024 items/block) + block totals.
__global__ void k_scan1(const int* __restrict__ deg, int* __restrict__ offs,
                        int* __restrict__ bsums, int n) {
    __shared__ int tmp[1024];
    int gid = blockIdx.x * 1024 + threadIdx.x;
    int v = (gid < n) ? deg[gid] : 0;
    tmp[threadIdx.x] = v;
    __syncthreads();
    // Hillis-Steele inclusive scan
    for (int off = 1; off < 1024; off <<= 1) {
        int t = (threadIdx.x >= off) ? tmp[threadIdx.x - off] : 0;
        __syncthreads();
        tmp[threadIdx.x] += t;
        __syncthreads();
    }
    int incl = tmp[threadIdx.x];
    if (gid < n) offs[gid] = incl - v;  // exclusive
    if (threadIdx.x == 1023) bsums[blockIdx.x] = incl;
}

// Serial exclusive scan of the (<=128) block sums.
__global__ void k_scan2(int* __restrict__ bsums, int nb) {
    int acc = 0;
    for (int i = 0; i < nb; i++) { int v = bsums[i]; bsums[i] = acc; acc += v; }
}

// Finalize offsets; init cursor; compute dinv = rsqrt(deg+1) and xd = x*dinv.
__global__ void k_scan3(int* __restrict__ offs, int* __restrict__ cursor,
                        const int* __restrict__ bsums, const int* __restrict__ deg,
                        const float* __restrict__ x, float* __restrict__ dinv,
                        float* __restrict__ xd, int n) {
    int i = blockIdx.x * blockDim.x + threadIdx.x;
    if (i >= n) return;
    int o = offs[i] + bsums[i >> 10];
    offs[i] = o;
    cursor[i] = o;
    float di = rsqrtf((float)deg[i] + 1.0f);  // +1: self loop
    dinv[i] = di;
    xd[i] = x[i] * di;
}

__global__ void k_scatter(const int* __restrict__ src, const int* __restrict__ dst,
                          int* __restrict__ cursor, int* __restrict__ csr, int E) {
    int e = blockIdx.x * blockDim.x + threadIdx.x;
    if (e >= E) return;
    int pos = atomicAdd(&cursor[dst[e]], 1);
    csr[pos] = src[e];
}

// Layer-1 scalar aggregation: agg1[i] = dinv[i]*(xd[i] + sum_j xd[j]).
__global__ void k_agg1(const float* __restrict__ xd, const float* __restrict__ dinv,
                       const int* __restrict__ offs, const int* __restrict__ deg,
                       const int* __restrict__ csr, float* __restrict__ agg1, int n) {
    int i = blockIdx.x * blockDim.x + threadIdx.x;
    if (i >= n) return;
    float t = xd[i];
    int o = offs[i], e = o + deg[i];
    for (int k = o; k < e; k++) t += xd[csr[k]];
    agg1[i] = t * dinv[i];
}

// h2s[i][f] = dinv[i] * sum_k relu(agg1[i]*W1[k]+b1[k]) * W2[k][f]
// One wave per row (lane = output feature f), 4 rows per 256-thread block.
__launch_bounds__(256)
__global__ void k_h2s(const float* __restrict__ agg1, const float* __restrict__ dinv,
                      const float* __restrict__ W1, const float* __restrict__ b1,
                      const float* __restrict__ W2, float* __restrict__ h2s, int n) {
    __shared__ float sW2[64 * 64];
    __shared__ float sW1[64];
    __shared__ float sb1[64];
    __shared__ float h1row[4][64];
    for (int i = threadIdx.x; i < 64 * 64; i += 256) sW2[i] = W2[i];
    if (threadIdx.x < 64) { sW1[threadIdx.x] = W1[threadIdx.x]; sb1[threadIdx.x] = b1[threadIdx.x]; }
    __syncthreads();
    int wave = threadIdx.x >> 6, lane = threadIdx.x & 63;
    int row = blockIdx.x * 4 + wave;
    bool active = row < n;
    float a = active ? agg1[row] : 0.0f;
    h1row[wave][lane] = fmaxf(fmaf(a, sW1[lane], sb1[lane]), 0.0f);
    __syncthreads();
    float acc = 0.0f;
#pragma unroll
    for (int k = 0; k < 64; k++)
        acc = fmaf(h1row[wave][k], sW2[k * 64 + lane], acc);
    if (active) h2s[(size_t)row * 64 + lane] = acc * dinv[row];
}

// Layer-2 gather + fused epilogue:
// out[i] = bh + sum_f Wh[f]*relu(b2[f] + dinv[i]*(h2s[i][f] + sum_j h2s[j][f]))
__launch_bounds__(256)
__global__ void k_out(const float* __restrict__ h2s, const float* __restrict__ dinv,
                      const float* __restrict__ b2, const float* __restrict__ Wh,
                      const float* __restrict__ bh, const int* __restrict__ offs,
                      const int* __restrict__ deg, const int* __restrict__ csr,
                      float* __restrict__ out, int n) {
    int wave = threadIdx.x >> 6, lane = threadIdx.x & 63;
    int i = blockIdx.x * 4 + wave;
    if (i >= n) return;
    float acc = h2s[(size_t)i * 64 + lane];  // self loop term
    int o = offs[i], e = o + deg[i];
    for (int k = o; k < e; k++) {
        int j = csr[k];                       // broadcast read (same addr across wave)
        acc += h2s[(size_t)j * 64 + lane];    // coalesced 256B row read
    }
    float v = fmaxf(fmaf(acc, dinv[i], b2[lane]), 0.0f) * Wh[lane];
    for (int off = 32; off; off >>= 1) v += __shfl_down(v, off, 64);
    if (lane == 0) out[i] = v + bh[0];
}

static inline size_t align_up(size_t x, size_t a) { return (x + a - 1) & ~(a - 1); }

extern "C" void kernel_launch(void* const* d_in, const int* in_sizes, int n_in,
                              void* d_out, int out_size, void* d_ws, size_t ws_size,
                              hipStream_t stream) {
    const float* x  = (const float*)d_in[0];
    const int*   ei = (const int*)d_in[1];   // [2, E] int
    const float* W1 = (const float*)d_in[2];
    const float* b1 = (const float*)d_in[3];
    const float* W2 = (const float*)d_in[4];
    const float* b2 = (const float*)d_in[5];
    const float* Wh = (const float*)d_in[6];
    const float* bh = (const float*)d_in[7];
    float* out = (float*)d_out;

    int n = in_sizes[0];        // 100000 (x is [N,1])
    int E = in_sizes[1] / 2;    // 1600000
    const int* srcp = ei;
    const int* dstp = ei + E;

    // workspace carve
    char* w = (char*)d_ws;
    size_t ni = align_up((size_t)n * sizeof(int), 256);
    size_t nf = align_up((size_t)n * sizeof(float), 256);
    int*   deg    = (int*)w;   w += ni;
    int*   offs   = (int*)w;   w += ni;
    int*   cursor = (int*)w;   w += ni;
    int*   bsums  = (int*)w;   w += align_up(256 * sizeof(int), 256);
    float* dinv   = (float*)w; w += nf;
    float* xd     = (float*)w; w += nf;
    float* agg1   = (float*)w; w += nf;
    int*   csr    = (int*)w;   w += align_up((size_t)E * sizeof(int), 256);
    float* h2s    = (float*)w; w += align_up((size_t)n * 64 * sizeof(float), 256);

    int nb1024 = (n + 1023) / 1024;
    int nb256n = (n + 255) / 256;
    int nb256e = (E + 255) / 256;
    int nb4    = (n + 3) / 4;

    k_zero<<<nb256n, 256, 0, stream>>>(deg, n);
    k_deg<<<nb256e, 256, 0, stream>>>(dstp, deg, E);
    k_scan1<<<nb1024, 1024, 0, stream>>>(deg, offs, bsums, n);
    k_scan2<<<1, 1, 0, stream>>>(bsums, nb1024);
    k_scan3<<<nb256n, 256, 0, stream>>>(offs, cursor, bsums, deg, x, dinv, xd, n);
    k_scatter<<<nb256e, 256, 0, stream>>>(srcp, dstp, cursor, csr, E);
    k_agg1<<<nb256n, 256, 0, stream>>>(xd, dinv, offs, deg, csr, agg1, n);
    k_h2s<<<nb4, 256, 0, stream>>>(agg1, dinv, W1, b1, W2, h2s, n);
    k_out<<<nb4, 256, 0, stream>>>(h2s, dinv, b2, Wh, bh, offs, deg, csr, out, n);
}

// Round 2
// 436.027 us; speedup vs baseline: 1.1446x; 1.1446x over previous
//
#include <hip/hip_runtime.h>

// GCN 2-layer fused pipeline for MI355X — round 2.
// Changes vs round 1: MLP-8 unrolled gather in k_out (shfl-broadcast indices),
// 16-lane-subwave parallel layer-1 aggregation, 16-rows/block k_h2s,
// int4-vectorized edge kernels, parallel second-level scan.

__global__ void k_zero(int* __restrict__ p, int n) {
    int i = blockIdx.x * blockDim.x + threadIdx.x;
    if (i < n) p[i] = 0;
}

__global__ void k_deg(const int* __restrict__ dst, int* __restrict__ deg, int E) {
    int e = (blockIdx.x * blockDim.x + threadIdx.x) * 4;
    if (e + 3 < E) {
        int4 v = *reinterpret_cast<const int4*>(dst + e);
        atomicAdd(&deg[v.x], 1);
        atomicAdd(&deg[v.y], 1);
        atomicAdd(&deg[v.z], 1);
        atomicAdd(&deg[v.w], 1);
    } else {
        for (int k = e; k < E; k++) atomicAdd(&deg[dst[k]], 1);
    }
}

// Per-block exclusive scan (1024 items/block) + block totals.
__global__ void k_scan1(const int* __restrict__ deg, int* __restrict__ offs,
                        int* __restrict__ bsums, int n) {
    __shared__ int tmp[1024];
    int gid = blockIdx.x * 1024 + threadIdx.x;
    int v = (gid < n) ? deg[gid] : 0;
    tmp[threadIdx.x] = v;
    __syncthreads();
    for (int off = 1; off < 1024; off <<= 1) {
        int t = (threadIdx.x >= off) ? tmp[threadIdx.x - off] : 0;
        __syncthreads();
        tmp[threadIdx.x] += t;
        __syncthreads();
    }
    int incl = tmp[threadIdx.x];
    if (gid < n) offs[gid] = incl - v;  // exclusive
    if (threadIdx.x == 1023) bsums[blockIdx.x] = incl;
}

// Parallel exclusive scan of the (<=1024) block sums; one block of 1024.
__global__ void k_scan2(int* __restrict__ bsums, int nb) {
    __shared__ int tmp[1024];
    int v = (threadIdx.x < nb) ? bsums[threadIdx.x] : 0;
    tmp[threadIdx.x] = v;
    __syncthreads();
    for (int off = 1; off < 1024; off <<= 1) {
        int t = (threadIdx.x >= off) ? tmp[threadIdx.x - off] : 0;
        __syncthreads();
        tmp[threadIdx.x] += t;
        __syncthreads();
    }
    if (threadIdx.x < nb) bsums[threadIdx.x] = tmp[threadIdx.x] - v;  // exclusive
}

// Finalize offsets; init cursor; compute dinv = rsqrt(deg+1) and xd = x*dinv.
__global__ void k_scan3(int* __restrict__ offs, int* __restrict__ cursor,
                        const int* __restrict__ bsums, const int* __restrict__ deg,
                        const float* __restrict__ x, float* __restrict__ dinv,
                        float* __restrict__ xd, int n) {
    int i = blockIdx.x * blockDim.x + threadIdx.x;
    if (i >= n) return;
    int o = offs[i] + bsums[i >> 10];
    offs[i] = o;
    cursor[i] = o;
    float di = rsqrtf((float)deg[i] + 1.0f);  // +1: self loop
    dinv[i] = di;
    xd[i] = x[i] * di;
}

__global__ void k_scatter(const int* __restrict__ src, const int* __restrict__ dst,
                          int* __restrict__ cursor, int* __restrict__ csr, int E) {
    int e = (blockIdx.x * blockDim.x + threadIdx.x) * 4;
    if (e + 3 < E) {
        int4 s = *reinterpret_cast<const int4*>(src + e);
        int4 d = *reinterpret_cast<const int4*>(dst + e);
        int p0 = atomicAdd(&cursor[d.x], 1); csr[p0] = s.x;
        int p1 = atomicAdd(&cursor[d.y], 1); csr[p1] = s.y;
        int p2 = atomicAdd(&cursor[d.z], 1); csr[p2] = s.z;
        int p3 = atomicAdd(&cursor[d.w], 1); csr[p3] = s.w;
    } else {
        for (int k = e; k < E; k++) {
            int pos = atomicAdd(&cursor[dst[k]], 1);
            csr[pos] = src[k];
        }
    }
}

// Layer-1 scalar aggregation, 16 lanes per node (4 nodes per wave):
// agg1[i] = dinv[i]*(xd[i] + sum_j xd[j]).
__global__ void k_agg1(const float* __restrict__ xd, const float* __restrict__ dinv,
                       const int* __restrict__ offs, const int* __restrict__ deg,
                       const int* __restrict__ csr, float* __restrict__ agg1, int n) {
    int t = blockIdx.x * blockDim.x + threadIdx.x;
    int g = t >> 4;   // node id
    int l = t & 15;   // lane within 16-lane group
    if (g >= n) return;
    int o = offs[g], d = deg[g];
    float s = 0.0f;
    for (int k = l; k < d; k += 16) s += xd[csr[o + k]];
    s += __shfl_xor(s, 8, 64);
    s += __shfl_xor(s, 4, 64);
    s += __shfl_xor(s, 2, 64);
    s += __shfl_xor(s, 1, 64);
    if (l == 0) agg1[g] = (s + xd[g]) * dinv[g];
}

// h2s[r][f] = dinv[r] * sum_k relu(agg1[r]*W1[k]+b1[k]) * W2[k][f]
// 16 rows per block: 4 waves x 4 rows/wave; W2 staged once per block.
__launch_bounds__(256)
__global__ void k_h2s(const float* __restrict__ agg1, const float* __restrict__ dinv,
                      const float* __restrict__ W1, const float* __restrict__ b1,
                      const float* __restrict__ W2, float* __restrict__ h2s, int n) {
    __shared__ float sW2[64 * 64];
    __shared__ float sW1[64];
    __shared__ float sb1[64];
    __shared__ float h1s[4][4][64];
    for (int i = threadIdx.x; i < 64 * 64; i += 256) sW2[i] = W2[i];
    if (threadIdx.x < 64) { sW1[threadIdx.x] = W1[threadIdx.x]; sb1[threadIdx.x] = b1[threadIdx.x]; }
    __syncthreads();
    int wave = threadIdx.x >> 6, lane = threadIdx.x & 63;
    int r0 = blockIdx.x * 16 + wave * 4;
#pragma unroll
    for (int rr = 0; rr < 4; rr++) {
        int r = r0 + rr;
        float a = (r < n) ? agg1[r] : 0.0f;
        h1s[wave][rr][lane] = fmaxf(fmaf(a, sW1[lane], sb1[lane]), 0.0f);
    }
    __syncthreads();
    float acc[4] = {0.0f, 0.0f, 0.0f, 0.0f};
#pragma unroll
    for (int k = 0; k < 64; k++) {
        float w = sW2[k * 64 + lane];
#pragma unroll
        for (int rr = 0; rr < 4; rr++) acc[rr] = fmaf(h1s[wave][rr][k], w, acc[rr]);
    }
#pragma unroll
    for (int rr = 0; rr < 4; rr++) {
        int r = r0 + rr;
        if (r < n) h2s[(size_t)r * 64 + lane] = acc[rr] * dinv[r];
    }
}

// Layer-2 gather + fused epilogue, MLP-8:
// out[i] = bh + sum_f Wh[f]*relu(b2[f] + dinv[i]*(h2s[i][f] + sum_j h2s[j][f]))
__launch_bounds__(256)
__global__ void k_out(const float* __restrict__ h2s, const float* __restrict__ dinv,
                      const float* __restrict__ b2, const float* __restrict__ Wh,
                      const float* __restrict__ bh, const int* __restrict__ offs,
                      const int* __restrict__ deg, const int* __restrict__ csr,
                      float* __restrict__ out, int n) {
    int wave = threadIdx.x >> 6, lane = threadIdx.x & 63;
    int i = blockIdx.x * 4 + wave;
    if (i >= n) return;
    int o = offs[i], d = deg[i];
    float a0 = 0, a1 = 0, a2 = 0, a3 = 0, a4 = 0, a5 = 0, a6 = 0, a7 = 0;
    for (int base = 0; base < d; base += 64) {
        int idx = csr[o + base + lane];   // one coalesced load covers 64 neighbors (padded)
        int m = min(64, d - base);
        int k = 0;
        for (; k + 8 <= m; k += 8) {
            int j0 = __shfl(idx, k + 0, 64), j1 = __shfl(idx, k + 1, 64);
            int j2 = __shfl(idx, k + 2, 64), j3 = __shfl(idx, k + 3, 64);
            int j4 = __shfl(idx, k + 4, 64), j5 = __shfl(idx, k + 5, 64);
            int j6 = __shfl(idx, k + 6, 64), j7 = __shfl(idx, k + 7, 64);
            a0 += h2s[(size_t)j0 * 64 + lane];
            a1 += h2s[(size_t)j1 * 64 + lane];
            a2 += h2s[(size_t)j2 * 64 + lane];
            a3 += h2s[(size_t)j3 * 64 + lane];
            a4 += h2s[(size_t)j4 * 64 + lane];
            a5 += h2s[(size_t)j5 * 64 + lane];
            a6 += h2s[(size_t)j6 * 64 + lane];
            a7 += h2s[(size_t)j7 * 64 + lane];
        }
        for (; k < m; k++) {
            int j = __shfl(idx, k, 64);
            a0 += h2s[(size_t)j * 64 + lane];
        }
    }
    float acc = h2s[(size_t)i * 64 + lane] + ((a0 + a1) + (a2 + a3)) + ((a4 + a5) + (a6 + a7));
    float v = fmaxf(fmaf(acc, dinv[i], b2[lane]), 0.0f) * Wh[lane];
    for (int off = 32; off; off >>= 1) v += __shfl_down(v, off, 64);
    if (lane == 0) out[i] = v + bh[0];
}

static inline size_t align_up(size_t x, size_t a) { return (x + a - 1) & ~(a - 1); }

extern "C" void kernel_launch(void* const* d_in, const int* in_sizes, int n_in,
                              void* d_out, int out_size, void* d_ws, size_t ws_size,
                              hipStream_t stream) {
    const float* x  = (const float*)d_in[0];
    const int*   ei = (const int*)d_in[1];   // [2, E]
    const float* W1 = (const float*)d_in[2];
    const float* b1 = (const float*)d_in[3];
    const float* W2 = (const float*)d_in[4];
    const float* b2 = (const float*)d_in[5];
    const float* Wh = (const float*)d_in[6];
    const float* bh = (const float*)d_in[7];
    float* out = (float*)d_out;

    int n = in_sizes[0];        // 100000
    int E = in_sizes[1] / 2;    // 1600000
    const int* srcp = ei;
    const int* dstp = ei + E;

    // workspace carve
    char* w = (char*)d_ws;
    size_t ni = align_up((size_t)n * sizeof(int), 256);
    size_t nf = align_up((size_t)n * sizeof(float), 256);
    int*   deg    = (int*)w;   w += ni;
    int*   offs   = (int*)w;   w += ni;
    int*   cursor = (int*)w;   w += ni;
    int*   bsums  = (int*)w;   w += align_up(1024 * sizeof(int), 256);
    float* dinv   = (float*)w; w += nf;
    float* xd     = (float*)w; w += nf;
    float* agg1   = (float*)w; w += nf;
    int*   csr    = (int*)w;   w += align_up(((size_t)E + 64) * sizeof(int), 256);
    float* h2s    = (float*)w; w += align_up((size_t)n * 64 * sizeof(float), 256);

    int nb1024 = (n + 1023) / 1024;
    int nb256n = (n + 255) / 256;
    int nbE4   = (E / 4 + 255) / 256 + 1;
    int nb4    = (n + 3) / 4;
    int nb16   = (n + 15) / 16;
    int nbAgg  = ((size_t)n * 16 + 255) / 256;

    k_zero<<<nb256n, 256, 0, stream>>>(deg, n);
    k_deg<<<nbE4, 256, 0, stream>>>(dstp, deg, E);
    k_scan1<<<nb1024, 1024, 0, stream>>>(deg, offs, bsums, n);
    k_scan2<<<1, 1024, 0, stream>>>(bsums, nb1024);
    k_scan3<<<nb256n, 256, 0, stream>>>(offs, cursor, bsums, deg, x, dinv, xd, n);
    k_scatter<<<nbE4, 256, 0, stream>>>(srcp, dstp, cursor, csr, E);
    k_agg1<<<nbAgg, 256, 0, stream>>>(xd, dinv, offs, deg, csr, agg1, n);
    k_h2s<<<nb16, 256, 0, stream>>>(agg1, dinv, W1, b1, W2, h2s, n);
    k_out<<<nb4, 256, 0, stream>>>(h2s, dinv, b2, Wh, bh, offs, deg, csr, out, n);
}

// Round 3
// 374.869 us; speedup vs baseline: 1.3313x; 1.1631x over previous
//
#include <hip/hip_runtime.h>

// GCN 2-layer fused pipeline for MI355X — round 3.
// Change vs round 2: XCD-partitioned CSR scatter. Partition p = blockIdx&7
// owns a contiguous dst range; its csr/cursor slice stays L2-resident on one
// XCD, converting ~108 MB of random HBM line-writes into ~6 MB of dense
// writeback. Edge list is re-read once per partition (L3-served).

__global__ void k_zero(int* __restrict__ p, int n) {
    int i = blockIdx.x * blockDim.x + threadIdx.x;
    if (i < n) p[i] = 0;
}

__global__ void k_deg(const int* __restrict__ dst, int* __restrict__ deg, int E) {
    int e = (blockIdx.x * blockDim.x + threadIdx.x) * 4;
    if (e + 3 < E) {
        int4 v = *reinterpret_cast<const int4*>(dst + e);
        atomicAdd(&deg[v.x], 1);
        atomicAdd(&deg[v.y], 1);
        atomicAdd(&deg[v.z], 1);
        atomicAdd(&deg[v.w], 1);
    } else {
        for (int k = e; k < E; k++) atomicAdd(&deg[dst[k]], 1);
    }
}

// Per-block exclusive scan (1024 items/block) + block totals.
__global__ void k_scan1(const int* __restrict__ deg, int* __restrict__ offs,
                        int* __restrict__ bsums, int n) {
    __shared__ int tmp[1024];
    int gid = blockIdx.x * 1024 + threadIdx.x;
    int v = (gid < n) ? deg[gid] : 0;
    tmp[threadIdx.x] = v;
    __syncthreads();
    for (int off = 1; off < 1024; off <<= 1) {
        int t = (threadIdx.x >= off) ? tmp[threadIdx.x - off] : 0;
        __syncthreads();
        tmp[threadIdx.x] += t;
        __syncthreads();
    }
    int incl = tmp[threadIdx.x];
    if (gid < n) offs[gid] = incl - v;  // exclusive
    if (threadIdx.x == 1023) bsums[blockIdx.x] = incl;
}

// Parallel exclusive scan of the (<=1024) block sums; one block of 1024.
__global__ void k_scan2(int* __restrict__ bsums, int nb) {
    __shared__ int tmp[1024];
    int v = (threadIdx.x < nb) ? bsums[threadIdx.x] : 0;
    tmp[threadIdx.x] = v;
    __syncthreads();
    for (int off = 1; off < 1024; off <<= 1) {
        int t = (threadIdx.x >= off) ? tmp[threadIdx.x - off] : 0;
        __syncthreads();
        tmp[threadIdx.x] += t;
        __syncthreads();
    }
    if (threadIdx.x < nb) bsums[threadIdx.x] = tmp[threadIdx.x] - v;  // exclusive
}

// Finalize offsets; init cursor; compute dinv = rsqrt(deg+1) and xd = x*dinv.
__global__ void k_scan3(int* __restrict__ offs, int* __restrict__ cursor,
                        const int* __restrict__ bsums, const int* __restrict__ deg,
                        const float* __restrict__ x, float* __restrict__ dinv,
                        float* __restrict__ xd, int n) {
    int i = blockIdx.x * blockDim.x + threadIdx.x;
    if (i >= n) return;
    int o = offs[i] + bsums[i >> 10];
    offs[i] = o;
    cursor[i] = o;
    float di = rsqrtf((float)deg[i] + 1.0f);  // +1: self loop
    dinv[i] = di;
    xd[i] = x[i] * di;
}

// XCD-partitioned scatter: partition p = blockIdx&7 handles dst in
// [p*npp, (p+1)*npp). Its csr slice is contiguous and L2-resident on XCD p
// (round-robin blockIdx->XCD); locality heuristic only, correctness-independent.
__global__ void k_scatter(const int* __restrict__ src, const int* __restrict__ dst,
                          int* __restrict__ cursor, int* __restrict__ csr,
                          int E, int npp) {
    int p = blockIdx.x & 7;
    int chunk = blockIdx.x >> 3;
    int e = (chunk * blockDim.x + threadIdx.x) * 4;
    int lo = p * npp, hi = lo + npp;
    if (e + 3 < E) {
        int4 d = *reinterpret_cast<const int4*>(dst + e);
        int4 s = *reinterpret_cast<const int4*>(src + e);
        if (d.x >= lo && d.x < hi) csr[atomicAdd(&cursor[d.x], 1)] = s.x;
        if (d.y >= lo && d.y < hi) csr[atomicAdd(&cursor[d.y], 1)] = s.y;
        if (d.z >= lo && d.z < hi) csr[atomicAdd(&cursor[d.z], 1)] = s.z;
        if (d.w >= lo && d.w < hi) csr[atomicAdd(&cursor[d.w], 1)] = s.w;
    } else {
        for (int k = e; k < E; k++) {
            int dd = dst[k];
            if (dd >= lo && dd < hi) csr[atomicAdd(&cursor[dd], 1)] = src[k];
        }
    }
}

// Layer-1 scalar aggregation, 16 lanes per node (4 nodes per wave):
// agg1[i] = dinv[i]*(xd[i] + sum_j xd[j]).
__global__ void k_agg1(const float* __restrict__ xd, const float* __restrict__ dinv,
                       const int* __restrict__ offs, const int* __restrict__ deg,
                       const int* __restrict__ csr, float* __restrict__ agg1, int n) {
    int t = blockIdx.x * blockDim.x + threadIdx.x;
    int g = t >> 4;   // node id
    int l = t & 15;   // lane within 16-lane group
    if (g >= n) return;
    int o = offs[g], d = deg[g];
    float s = 0.0f;
    for (int k = l; k < d; k += 16) s += xd[csr[o + k]];
    s += __shfl_xor(s, 8, 64);
    s += __shfl_xor(s, 4, 64);
    s += __shfl_xor(s, 2, 64);
    s += __shfl_xor(s, 1, 64);
    if (l == 0) agg1[g] = (s + xd[g]) * dinv[g];
}

// h2s[r][f] = dinv[r] * sum_k relu(agg1[r]*W1[k]+b1[k]) * W2[k][f]
// 16 rows per block: 4 waves x 4 rows/wave; W2 staged once per block.
__launch_bounds__(256)
__global__ void k_h2s(const float* __restrict__ agg1, const float* __restrict__ dinv,
                      const float* __restrict__ W1, const float* __restrict__ b1,
                      const float* __restrict__ W2, float* __restrict__ h2s, int n) {
    __shared__ float sW2[64 * 64];
    __shared__ float sW1[64];
    __shared__ float sb1[64];
    __shared__ float h1s[4][4][64];
    for (int i = threadIdx.x; i < 64 * 64; i += 256) sW2[i] = W2[i];
    if (threadIdx.x < 64) { sW1[threadIdx.x] = W1[threadIdx.x]; sb1[threadIdx.x] = b1[threadIdx.x]; }
    __syncthreads();
    int wave = threadIdx.x >> 6, lane = threadIdx.x & 63;
    int r0 = blockIdx.x * 16 + wave * 4;
#pragma unroll
    for (int rr = 0; rr < 4; rr++) {
        int r = r0 + rr;
        float a = (r < n) ? agg1[r] : 0.0f;
        h1s[wave][rr][lane] = fmaxf(fmaf(a, sW1[lane], sb1[lane]), 0.0f);
    }
    __syncthreads();
    float acc[4] = {0.0f, 0.0f, 0.0f, 0.0f};
#pragma unroll
    for (int k = 0; k < 64; k++) {
        float w = sW2[k * 64 + lane];
#pragma unroll
        for (int rr = 0; rr < 4; rr++) acc[rr] = fmaf(h1s[wave][rr][k], w, acc[rr]);
    }
#pragma unroll
    for (int rr = 0; rr < 4; rr++) {
        int r = r0 + rr;
        if (r < n) h2s[(size_t)r * 64 + lane] = acc[rr] * dinv[r];
    }
}

// Layer-2 gather + fused epilogue, MLP-8:
// out[i] = bh + sum_f Wh[f]*relu(b2[f] + dinv[i]*(h2s[i][f] + sum_j h2s[j][f]))
__launch_bounds__(256)
__global__ void k_out(const float* __restrict__ h2s, const float* __restrict__ dinv,
                      const float* __restrict__ b2, const float* __restrict__ Wh,
                      const float* __restrict__ bh, const int* __restrict__ offs,
                      const int* __restrict__ deg, const int* __restrict__ csr,
                      float* __restrict__ out, int n) {
    int wave = threadIdx.x >> 6, lane = threadIdx.x & 63;
    int i = blockIdx.x * 4 + wave;
    if (i >= n) return;
    int o = offs[i], d = deg[i];
    float a0 = 0, a1 = 0, a2 = 0, a3 = 0, a4 = 0, a5 = 0, a6 = 0, a7 = 0;
    for (int base = 0; base < d; base += 64) {
        int idx = csr[o + base + lane];   // one coalesced load covers 64 neighbors (padded)
        int m = min(64, d - base);
        int k = 0;
        for (; k + 8 <= m; k += 8) {
            int j0 = __shfl(idx, k + 0, 64), j1 = __shfl(idx, k + 1, 64);
            int j2 = __shfl(idx, k + 2, 64), j3 = __shfl(idx, k + 3, 64);
            int j4 = __shfl(idx, k + 4, 64), j5 = __shfl(idx, k + 5, 64);
            int j6 = __shfl(idx, k + 6, 64), j7 = __shfl(idx, k + 7, 64);
            a0 += h2s[(size_t)j0 * 64 + lane];
            a1 += h2s[(size_t)j1 * 64 + lane];
            a2 += h2s[(size_t)j2 * 64 + lane];
            a3 += h2s[(size_t)j3 * 64 + lane];
            a4 += h2s[(size_t)j4 * 64 + lane];
            a5 += h2s[(size_t)j5 * 64 + lane];
            a6 += h2s[(size_t)j6 * 64 + lane];
            a7 += h2s[(size_t)j7 * 64 + lane];
        }
        for (; k < m; k++) {
            int j = __shfl(idx, k, 64);
            a0 += h2s[(size_t)j * 64 + lane];
        }
    }
    float acc = h2s[(size_t)i * 64 + lane] + ((a0 + a1) + (a2 + a3)) + ((a4 + a5) + (a6 + a7));
    float v = fmaxf(fmaf(acc, dinv[i], b2[lane]), 0.0f) * Wh[lane];
    for (int off = 32; off; off >>= 1) v += __shfl_down(v, off, 64);
    if (lane == 0) out[i] = v + bh[0];
}

static inline size_t align_up(size_t x, size_t a) { return (x + a - 1) & ~(a - 1); }

extern "C" void kernel_launch(void* const* d_in, const int* in_sizes, int n_in,
                              void* d_out, int out_size, void* d_ws, size_t ws_size,
                              hipStream_t stream) {
    const float* x  = (const float*)d_in[0];
    const int*   ei = (const int*)d_in[1];   // [2, E]
    const float* W1 = (const float*)d_in[2];
    const float* b1 = (const float*)d_in[3];
    const float* W2 = (const float*)d_in[4];
    const float* b2 = (const float*)d_in[5];
    const float* Wh = (const float*)d_in[6];
    const float* bh = (const float*)d_in[7];
    float* out = (float*)d_out;

    int n = in_sizes[0];        // 100000
    int E = in_sizes[1] / 2;    // 1600000
    const int* srcp = ei;
    const int* dstp = ei + E;

    // workspace carve
    char* w = (char*)d_ws;
    size_t ni = align_up((size_t)n * sizeof(int), 256);
    size_t nf = align_up((size_t)n * sizeof(float), 256);
    int*   deg    = (int*)w;   w += ni;
    int*   offs   = (int*)w;   w += ni;
    int*   cursor = (int*)w;   w += ni;
    int*   bsums  = (int*)w;   w += align_up(1024 * sizeof(int), 256);
    float* dinv   = (float*)w; w += nf;
    float* xd     = (float*)w; w += nf;
    float* agg1   = (float*)w; w += nf;
    int*   csr    = (int*)w;   w += align_up(((size_t)E + 64) * sizeof(int), 256);
    float* h2s    = (float*)w; w += align_up((size_t)n * 64 * sizeof(float), 256);

    int nb1024 = (n + 1023) / 1024;
    int nb256n = (n + 255) / 256;
    int nbE4   = (E / 4 + 255) / 256 + 1;
    int nb4    = (n + 3) / 4;
    int nb16   = (n + 15) / 16;
    int nbAgg  = ((size_t)n * 16 + 255) / 256;
    int npp    = (n + 7) / 8;          // nodes per partition
    int nbScat = nbE4 * 8;             // 8 partitions, p = blockIdx & 7

    k_zero<<<nb256n, 256, 0, stream>>>(deg, n);
    k_deg<<<nbE4, 256, 0, stream>>>(dstp, deg, E);
    k_scan1<<<nb1024, 1024, 0, stream>>>(deg, offs, bsums, n);
    k_scan2<<<1, 1024, 0, stream>>>(bsums, nb1024);
    k_scan3<<<nb256n, 256, 0, stream>>>(offs, cursor, bsums, deg, x, dinv, xd, n);
    k_scatter<<<nbScat, 256, 0, stream>>>(srcp, dstp, cursor, csr, E, npp);
    k_agg1<<<nbAgg, 256, 0, stream>>>(xd, dinv, offs, deg, csr, agg1, n);
    k_h2s<<<nb16, 256, 0, stream>>>(agg1, dinv, W1, b1, W2, h2s, n);
    k_out<<<nb4, 256, 0, stream>>>(h2s, dinv, b2, Wh, bh, offs, deg, csr, out, n);
}

// Round 5
// 342.514 us; speedup vs baseline: 1.4571x; 1.0945x over previous
//
#include <hip/hip_runtime.h>

// GCN 2-layer fused pipeline for MI355X — round 4 (resubmit; round-4 bench
// failed with GPUAcquisitionTimeout, no data).
// Changes vs round 3:
//  - k_h2s: h1 broadcasts via v_readlane (VALU) instead of LDS reads; was
//    LDS-pipe-bound at 320 ds_read/wave (85 us). W2 stays LDS-staged (b32,
//    2-way-free reads); float4 staging.
//  - k_deg: XCD-partitioned like k_scatter (atomics land in own-L2 slice).

__global__ void k_zero(int* __restrict__ p, int n) {
    int i = blockIdx.x * blockDim.x + threadIdx.x;
    if (i < n) p[i] = 0;
}

// XCD-partitioned degree count: partition p = blockIdx&7 counts dst in
// [p*npp,(p+1)*npp) only; its deg slice stays resident in that XCD's L2.
__global__ void k_deg(const int* __restrict__ dst, int* __restrict__ deg,
                      int E, int npp) {
    int p = blockIdx.x & 7;
    int chunk = blockIdx.x >> 3;
    int e = (chunk * blockDim.x + threadIdx.x) * 4;
    int lo = p * npp, hi = lo + npp;
    if (e + 3 < E) {
        int4 v = *reinterpret_cast<const int4*>(dst + e);
        if (v.x >= lo && v.x < hi) atomicAdd(&deg[v.x], 1);
        if (v.y >= lo && v.y < hi) atomicAdd(&deg[v.y], 1);
        if (v.z >= lo && v.z < hi) atomicAdd(&deg[v.z], 1);
        if (v.w >= lo && v.w < hi) atomicAdd(&deg[v.w], 1);
    } else {
        for (int k = e; k < E; k++) {
            int dd = dst[k];
            if (dd >= lo && dd < hi) atomicAdd(&deg[dd], 1);
        }
    }
}

// Per-block exclusive scan (1024 items/block) + block totals.
__global__ void k_scan1(const int* __restrict__ deg, int* __restrict__ offs,
                        int* __restrict__ bsums, int n) {
    __shared__ int tmp[1024];
    int gid = blockIdx.x * 1024 + threadIdx.x;
    int v = (gid < n) ? deg[gid] : 0;
    tmp[threadIdx.x] = v;
    __syncthreads();
    for (int off = 1; off < 1024; off <<= 1) {
        int t = (threadIdx.x >= off) ? tmp[threadIdx.x - off] : 0;
        __syncthreads();
        tmp[threadIdx.x] += t;
        __syncthreads();
    }
    int incl = tmp[threadIdx.x];
    if (gid < n) offs[gid] = incl - v;  // exclusive
    if (threadIdx.x == 1023) bsums[blockIdx.x] = incl;
}

// Parallel exclusive scan of the (<=1024) block sums; one block of 1024.
__global__ void k_scan2(int* __restrict__ bsums, int nb) {
    __shared__ int tmp[1024];
    int v = (threadIdx.x < nb) ? bsums[threadIdx.x] : 0;
    tmp[threadIdx.x] = v;
    __syncthreads();
    for (int off = 1; off < 1024; off <<= 1) {
        int t = (threadIdx.x >= off) ? tmp[threadIdx.x - off] : 0;
        __syncthreads();
        tmp[threadIdx.x] += t;
        __syncthreads();
    }
    if (threadIdx.x < nb) bsums[threadIdx.x] = tmp[threadIdx.x] - v;  // exclusive
}

// Finalize offsets; init cursor; compute dinv = rsqrt(deg+1) and xd = x*dinv.
__global__ void k_scan3(int* __restrict__ offs, int* __restrict__ cursor,
                        const int* __restrict__ bsums, const int* __restrict__ deg,
                        const float* __restrict__ x, float* __restrict__ dinv,
                        float* __restrict__ xd, int n) {
    int i = blockIdx.x * blockDim.x + threadIdx.x;
    if (i >= n) return;
    int o = offs[i] + bsums[i >> 10];
    offs[i] = o;
    cursor[i] = o;
    float di = rsqrtf((float)deg[i] + 1.0f);  // +1: self loop
    dinv[i] = di;
    xd[i] = x[i] * di;
}

// XCD-partitioned scatter: partition p = blockIdx&7 handles dst in
// [p*npp, (p+1)*npp); csr/cursor slice stays L2-resident on one XCD.
__global__ void k_scatter(const int* __restrict__ src, const int* __restrict__ dst,
                          int* __restrict__ cursor, int* __restrict__ csr,
                          int E, int npp) {
    int p = blockIdx.x & 7;
    int chunk = blockIdx.x >> 3;
    int e = (chunk * blockDim.x + threadIdx.x) * 4;
    int lo = p * npp, hi = lo + npp;
    if (e + 3 < E) {
        int4 d = *reinterpret_cast<const int4*>(dst + e);
        int4 s = *reinterpret_cast<const int4*>(src + e);
        if (d.x >= lo && d.x < hi) csr[atomicAdd(&cursor[d.x], 1)] = s.x;
        if (d.y >= lo && d.y < hi) csr[atomicAdd(&cursor[d.y], 1)] = s.y;
        if (d.z >= lo && d.z < hi) csr[atomicAdd(&cursor[d.z], 1)] = s.z;
        if (d.w >= lo && d.w < hi) csr[atomicAdd(&cursor[d.w], 1)] = s.w;
    } else {
        for (int k = e; k < E; k++) {
            int dd = dst[k];
            if (dd >= lo && dd < hi) csr[atomicAdd(&cursor[dd], 1)] = src[k];
        }
    }
}

// Layer-1 scalar aggregation, 16 lanes per node (4 nodes per wave):
// agg1[i] = dinv[i]*(xd[i] + sum_j xd[j]).
__global__ void k_agg1(const float* __restrict__ xd, const float* __restrict__ dinv,
                       const int* __restrict__ offs, const int* __restrict__ deg,
                       const int* __restrict__ csr, float* __restrict__ agg1, int n) {
    int t = blockIdx.x * blockDim.x + threadIdx.x;
    int g = t >> 4;   // node id
    int l = t & 15;   // lane within 16-lane group
    if (g >= n) return;
    int o = offs[g], d = deg[g];
    float s = 0.0f;
    for (int k = l; k < d; k += 16) s += xd[csr[o + k]];
    s += __shfl_xor(s, 8, 64);
    s += __shfl_xor(s, 4, 64);
    s += __shfl_xor(s, 2, 64);
    s += __shfl_xor(s, 1, 64);
    if (l == 0) agg1[g] = (s + xd[g]) * dinv[g];
}

// h2s[r][f] = dinv[r] * sum_k relu(agg1[r]*W1[k]+b1[k]) * W2[k][f]
// 16 rows/block (4 waves x 4 rows). h1 lives in registers (h1v[rr] on lane
// f); element k broadcast via v_readlane (constant lane idx, pure VALU) —
// no LDS broadcast reads. W2 staged in LDS, read b32 (2-way free).
__launch_bounds__(256)
__global__ void k_h2s(const float* __restrict__ agg1, const float* __restrict__ dinv,
                      const float* __restrict__ W1, const float* __restrict__ b1,
                      const float* __restrict__ W2, float* __restrict__ h2s, int n) {
    __shared__ float sW2[64 * 64];
    __shared__ float sW1[64];
    __shared__ float sb1[64];
    for (int i = threadIdx.x; i < 1024; i += 256)
        reinterpret_cast<float4*>(sW2)[i] = reinterpret_cast<const float4*>(W2)[i];
    if (threadIdx.x < 64) { sW1[threadIdx.x] = W1[threadIdx.x]; sb1[threadIdx.x] = b1[threadIdx.x]; }
    __syncthreads();
    int wave = threadIdx.x >> 6, lane = threadIdx.x & 63;
    int r0 = blockIdx.x * 16 + wave * 4;
    float w1l = sW1[lane], b1l = sb1[lane];
    float h1v[4];
#pragma unroll
    for (int rr = 0; rr < 4; rr++) {
        int r = r0 + rr;
        float a = (r < n) ? agg1[r] : 0.0f;
        h1v[rr] = fmaxf(fmaf(a, w1l, b1l), 0.0f);
    }
    float acc[4] = {0.0f, 0.0f, 0.0f, 0.0f};
#pragma unroll
    for (int k = 0; k < 64; k++) {
        float w = sW2[k * 64 + lane];
#pragma unroll
        for (int rr = 0; rr < 4; rr++) {
            float s = __int_as_float(__builtin_amdgcn_readlane(__float_as_int(h1v[rr]), k));
            acc[rr] = fmaf(s, w, acc[rr]);
        }
    }
#pragma unroll
    for (int rr = 0; rr < 4; rr++) {
        int r = r0 + rr;
        if (r < n) h2s[(size_t)r * 64 + lane] = acc[rr] * dinv[r];
    }
}

// Layer-2 gather + fused epilogue, MLP-8:
// out[i] = bh + sum_f Wh[f]*relu(b2[f] + dinv[i]*(h2s[i][f] + sum_j h2s[j][f]))
__launch_bounds__(256)
__global__ void k_out(const float* __restrict__ h2s, const float* __restrict__ dinv,
                      const float* __restrict__ b2, const float* __restrict__ Wh,
                      const float* __restrict__ bh, const int* __restrict__ offs,
                      const int* __restrict__ deg, const int* __restrict__ csr,
                      float* __restrict__ out, int n) {
    int wave = threadIdx.x >> 6, lane = threadIdx.x & 63;
    int i = blockIdx.x * 4 + wave;
    if (i >= n) return;
    int o = offs[i], d = deg[i];
    float a0 = 0, a1 = 0, a2 = 0, a3 = 0, a4 = 0, a5 = 0, a6 = 0, a7 = 0;
    for (int base = 0; base < d; base += 64) {
        int idx = csr[o + base + lane];   // one coalesced load covers 64 neighbors (padded)
        int m = min(64, d - base);
        int k = 0;
        for (; k + 8 <= m; k += 8) {
            int j0 = __shfl(idx, k + 0, 64), j1 = __shfl(idx, k + 1, 64);
            int j2 = __shfl(idx, k + 2, 64), j3 = __shfl(idx, k + 3, 64);
            int j4 = __shfl(idx, k + 4, 64), j5 = __shfl(idx, k + 5, 64);
            int j6 = __shfl(idx, k + 6, 64), j7 = __shfl(idx, k + 7, 64);
            a0 += h2s[(size_t)j0 * 64 + lane];
            a1 += h2s[(size_t)j1 * 64 + lane];
            a2 += h2s[(size_t)j2 * 64 + lane];
            a3 += h2s[(size_t)j3 * 64 + lane];
            a4 += h2s[(size_t)j4 * 64 + lane];
            a5 += h2s[(size_t)j5 * 64 + lane];
            a6 += h2s[(size_t)j6 * 64 + lane];
            a7 += h2s[(size_t)j7 * 64 + lane];
        }
        for (; k < m; k++) {
            int j = __shfl(idx, k, 64);
            a0 += h2s[(size_t)j * 64 + lane];
        }
    }
    float acc = h2s[(size_t)i * 64 + lane] + ((a0 + a1) + (a2 + a3)) + ((a4 + a5) + (a6 + a7));
    float v = fmaxf(fmaf(acc, dinv[i], b2[lane]), 0.0f) * Wh[lane];
    for (int off = 32; off; off >>= 1) v += __shfl_down(v, off, 64);
    if (lane == 0) out[i] = v + bh[0];
}

static inline size_t align_up(size_t x, size_t a) { return (x + a - 1) & ~(a - 1); }

extern "C" void kernel_launch(void* const* d_in, const int* in_sizes, int n_in,
                              void* d_out, int out_size, void* d_ws, size_t ws_size,
                              hipStream_t stream) {
    const float* x  = (const float*)d_in[0];
    const int*   ei = (const int*)d_in[1];   // [2, E]
    const float* W1 = (const float*)d_in[2];
    const float* b1 = (const float*)d_in[3];
    const float* W2 = (const float*)d_in[4];
    const float* b2 = (const float*)d_in[5];
    const float* Wh = (const float*)d_in[6];
    const float* bh = (const float*)d_in[7];
    float* out = (float*)d_out;

    int n = in_sizes[0];        // 100000
    int E = in_sizes[1] / 2;    // 1600000
    const int* srcp = ei;
    const int* dstp = ei + E;

    // workspace carve
    char* w = (char*)d_ws;
    size_t ni = align_up((size_t)n * sizeof(int), 256);
    size_t nf = align_up((size_t)n * sizeof(float), 256);
    int*   deg    = (int*)w;   w += ni;
    int*   offs   = (int*)w;   w += ni;
    int*   cursor = (int*)w;   w += ni;
    int*   bsums  = (int*)w;   w += align_up(1024 * sizeof(int), 256);
    float* dinv   = (float*)w; w += nf;
    float* xd     = (float*)w; w += nf;
    float* agg1   = (float*)w; w += nf;
    int*   csr    = (int*)w;   w += align_up(((size_t)E + 64) * sizeof(int), 256);
    float* h2s    = (float*)w; w += align_up((size_t)n * 64 * sizeof(float), 256);

    int nb1024 = (n + 1023) / 1024;
    int nb256n = (n + 255) / 256;
    int nbE4   = (E / 4 + 255) / 256 + 1;
    int nb4    = (n + 3) / 4;
    int nb16   = (n + 15) / 16;
    int nbAgg  = ((size_t)n * 16 + 255) / 256;
    int npp    = (n + 7) / 8;          // nodes per partition
    int nbScat = nbE4 * 8;             // 8 partitions, p = blockIdx & 7

    k_zero<<<nb256n, 256, 0, stream>>>(deg, n);
    k_deg<<<nbScat, 256, 0, stream>>>(dstp, deg, E, npp);
    k_scan1<<<nb1024, 1024, 0, stream>>>(deg, offs, bsums, n);
    k_scan2<<<1, 1024, 0, stream>>>(bsums, nb1024);
    k_scan3<<<nb256n, 256, 0, stream>>>(offs, cursor, bsums, deg, x, dinv, xd, n);
    k_scatter<<<nbScat, 256, 0, stream>>>(srcp, dstp, cursor, csr, E, npp);
    k_agg1<<<nbAgg, 256, 0, stream>>>(xd, dinv, offs, deg, csr, agg1, n);
    k_h2s<<<nb16, 256, 0, stream>>>(agg1, dinv, W1, b1, W2, h2s, n);
    k_out<<<nb4, 256, 0, stream>>>(h2s, dinv, b2, Wh, bh, offs, deg, csr, out, n);
}